// Round 5
// baseline (159.808 us; speedup 1.0000x reference)
//
#include <hip/hip_runtime.h>

#define B 2
#define N_P 2000
#define N_ALL 2048
#define N_REL 8192
#define N_INST 8
#define NF 128

typedef unsigned short u16;
typedef __attribute__((ext_vector_type(8))) short bf16x8;
typedef __attribute__((ext_vector_type(4))) float f32x4;

__device__ __forceinline__ u16 f2bf(float f) {
    union { float f; unsigned u; } v; v.f = f;
    unsigned r = v.u + 0x7FFFu + ((v.u >> 16) & 1u);
    return (u16)(r >> 16);
}
__device__ __forceinline__ float bf2f(u16 h) {
    union { unsigned u; float f; } v; v.u = ((unsigned)h) << 16; return v.f;
}

#define MFMA16(a, b, c) __builtin_amdgcn_mfma_f32_16x16x32_bf16((a), (b), (c), 0, 0, 0)

struct WtCvt {
    const float* src[10];
    int K[10];
    int Kpad[10];
    int cum[11];
};

// ---------------------------------------------------------------------------
// Deep scan body: wave handles 4 consecutive rows of one matrix; all 32
// float4 loads issued before any consume (forced MLP).
// ---------------------------------------------------------------------------
template<bool NT>
__device__ __forceinline__ void scan4(const float* __restrict__ M, int gw, int lane,
                                      int* __restrict__ out)
{
    int r0 = gw * 4;
    const f32x4* s = reinterpret_cast<const f32x4*>(M + (size_t)r0 * N_ALL) + lane;
    f32x4 v[4][8];
    #pragma unroll
    for (int r = 0; r < 4; ++r)
        #pragma unroll
        for (int i = 0; i < 8; ++i) {
            const f32x4* p = s + r * 512 + 64 * i;
            v[r][i] = NT ? __builtin_nontemporal_load(p) : *p;
        }
    int f[4];
    #pragma unroll
    for (int r = 0; r < 4; ++r) {
        f[r] = -1;
        #pragma unroll
        for (int i = 0; i < 8; ++i) {
            int bi = (lane + 64 * i) * 4;
            if (v[r][i].x != 0.f) f[r] = bi;
            if (v[r][i].y != 0.f) f[r] = bi + 1;
            if (v[r][i].z != 0.f) f[r] = bi + 2;
            if (v[r][i].w != 0.f) f[r] = bi + 3;
        }
    }
    #pragma unroll
    for (int off = 32; off; off >>= 1)
        #pragma unroll
        for (int r = 0; r < 4; ++r) f[r] = max(f[r], __shfl_xor(f[r], off));
    if (lane == 0) {
        int4 o; o.x = f[0]; o.y = f[1]; o.z = f[2]; o.w = f[3];
        *reinterpret_cast<int4*>(out + r0) = o;
    }
}

// ---------------------------------------------------------------------------
// PREP kernel, block-ranged fusion:
//   [0, 1024):      deep scan of Rr (4096 waves x 4 rows)
//   [1024, 1776):   weight convert fp32 [K][128] -> bf16 [128][Kpad]
//   [1776, 1792):   build p_inputs bf16 [B*N_ALL][32]
//   [1792, 3328):   zero 3 agg buffers
// ---------------------------------------------------------------------------
#define PREP_SCAN_BLKS 1024
#define PREP_CVT_BLKS  752
#define PREP_PIN_BLKS  16
#define PREP_ZERO_BLKS 1536
#define PREP_TOTAL (PREP_SCAN_BLKS + PREP_CVT_BLKS + PREP_PIN_BLKS + PREP_ZERO_BLKS)

__global__ __launch_bounds__(256, 1) void prep(
    const float* __restrict__ Rr,
    int* __restrict__ rr,
    WtCvt d, u16* __restrict__ wt, int wt_total,
    const float* __restrict__ state, const float* __restrict__ attrs,
    const float* __restrict__ action, const float* __restrict__ den,
    const float* __restrict__ phys, u16* __restrict__ P,
    float* __restrict__ aggz, int aggz_f4)
{
    int blk = blockIdx.x;
    if (blk < PREP_SCAN_BLKS) {
        int gw = blk * 4 + (threadIdx.x >> 6);   // 0..4095
        scan4<false>(Rr, gw, threadIdx.x & 63, rr);
        return;
    }
    blk -= PREP_SCAN_BLKS;
    if (blk < PREP_CVT_BLKS) {
        int t = blk * 256 + threadIdx.x;
        if (t >= wt_total) return;
        int m = 0;
        while (t >= d.cum[m + 1]) m++;
        int loc = t - d.cum[m];
        int Kp = d.Kpad[m];
        int c = loc / Kp, k = loc - c * Kp;
        float v = (k < d.K[m]) ? d.src[m][(size_t)k * NF + c] : 0.f;
        wt[t] = f2bf(v);
        return;
    }
    blk -= PREP_CVT_BLKS;
    if (blk < PREP_PIN_BLKS) {
        int t = blk * 256 + threadIdx.x;
        if (t >= B * N_ALL) return;
        int b = t >> 11, n = t & 2047;
        float o[19];
        o[0] = attrs[t * 2]; o[1] = attrs[t * 2 + 1];
        #pragma unroll
        for (int h = 0; h < 3; ++h)
            #pragma unroll
            for (int c = 0; c < 3; ++c)
                o[2 + h * 3 + c] = state[(((size_t)b * 4 + h + 1) * N_ALL + n) * 3 + c]
                                 - state[(((size_t)b * 4 + h)     * N_ALL + n) * 3 + c];
        #pragma unroll
        for (int c = 0; c < 3; ++c)
            o[11 + c] = state[(((size_t)b * 4 + 3) * N_ALL + n) * 3 + c];
        o[14] = (n < N_P) ? phys[b] : 0.f;
        #pragma unroll
        for (int c = 0; c < 3; ++c) o[15 + c] = action[t * 3 + c];
        o[18] = (n < N_P) ? den[b] : 0.f;
        u16* dst = P + (size_t)t * 32;
        #pragma unroll
        for (int k = 0; k < 19; ++k) dst[k] = f2bf(o[k]);
        #pragma unroll
        for (int k = 19; k < 32; ++k) dst[k] = 0;
        return;
    }
    blk -= PREP_PIN_BLKS;
    {
        int t = blk * 256 + threadIdx.x;
        if (t < aggz_f4) {
            f32x4 z = {0.f, 0.f, 0.f, 0.f};
            reinterpret_cast<f32x4*>(aggz)[t] = z;
        }
    }
}

// ---------------------------------------------------------------------------
// scan_rs: deep scan of Rs with nontemporal loads (A/B probe vs prep's Rr scan)
// ---------------------------------------------------------------------------
__global__ __launch_bounds__(256, 1) void scan_rs(
    const float* __restrict__ Rs, int* __restrict__ rs)
{
    int gw = blockIdx.x * 4 + (threadIdx.x >> 6);
    scan4<true>(Rs, gw, threadIdx.x & 63, rs);
}

// ---------------------------------------------------------------------------
// Shared 3-layer MLP body (wave = 16 rows x 128 cols)
// ---------------------------------------------------------------------------
template<int K0, bool ALDS>
__device__ __forceinline__ void enc_body(
    const u16* __restrict__ Xg, const u16* ri,
    const u16* __restrict__ wt0, const u16* __restrict__ wt1, const u16* __restrict__ wt2,
    const float* __restrict__ b0, const float* __restrict__ b1, const float* __restrict__ b2,
    u16* __restrict__ Y, int rbase, int w, int lane, u16* T0, u16* T1)
{
    int r16 = lane & 15, g4 = lane >> 4;
    f32x4 zero = {0.f, 0.f, 0.f, 0.f};
    f32x4 acc[8];
    #pragma unroll
    for (int cf = 0; cf < 8; ++cf) acc[cf] = zero;
    #pragma unroll
    for (int kf = 0; kf < K0 / 32; ++kf) {
        int kcol = kf * 32 + g4 * 8;
        bf16x8 a;
        if (ALDS) {
            int lr = w * 16 + r16;
            a = *reinterpret_cast<const bf16x8*>(&ri[lr * K0 + (kcol ^ ((lr & 7) << 3))]);
        } else {
            a = *reinterpret_cast<const bf16x8*>(Xg + (size_t)(rbase + r16) * K0 + kcol);
        }
        #pragma unroll
        for (int cf = 0; cf < 8; ++cf) {
            bf16x8 bv = *reinterpret_cast<const bf16x8*>(wt0 + (size_t)(cf * 16 + r16) * K0 + kcol);
            acc[cf] = MFMA16(a, bv, acc[cf]);
        }
    }
    #pragma unroll
    for (int cf = 0; cf < 8; ++cf) {
        float bv = b0[cf * 16 + r16];
        #pragma unroll
        for (int i = 0; i < 4; ++i) {
            int row = g4 * 4 + i, col = cf * 16 + r16;
            T0[row * NF + (col ^ ((row & 7) << 3))] = f2bf(fmaxf(acc[cf][i] + bv, 0.f));
        }
    }
    #pragma unroll
    for (int cf = 0; cf < 8; ++cf) acc[cf] = zero;
    #pragma unroll
    for (int kf = 0; kf < 4; ++kf) {
        int kcol = kf * 32 + g4 * 8;
        bf16x8 a = *reinterpret_cast<const bf16x8*>(&T0[r16 * NF + (kcol ^ ((r16 & 7) << 3))]);
        #pragma unroll
        for (int cf = 0; cf < 8; ++cf) {
            bf16x8 bv = *reinterpret_cast<const bf16x8*>(wt1 + (size_t)(cf * 16 + r16) * NF + kcol);
            acc[cf] = MFMA16(a, bv, acc[cf]);
        }
    }
    #pragma unroll
    for (int cf = 0; cf < 8; ++cf) {
        float bv = b1[cf * 16 + r16];
        #pragma unroll
        for (int i = 0; i < 4; ++i) {
            int row = g4 * 4 + i, col = cf * 16 + r16;
            T1[row * NF + (col ^ ((row & 7) << 3))] = f2bf(fmaxf(acc[cf][i] + bv, 0.f));
        }
    }
    #pragma unroll
    for (int cf = 0; cf < 8; ++cf) acc[cf] = zero;
    #pragma unroll
    for (int kf = 0; kf < 4; ++kf) {
        int kcol = kf * 32 + g4 * 8;
        bf16x8 a = *reinterpret_cast<const bf16x8*>(&T1[r16 * NF + (kcol ^ ((r16 & 7) << 3))]);
        #pragma unroll
        for (int cf = 0; cf < 8; ++cf) {
            bf16x8 bv = *reinterpret_cast<const bf16x8*>(wt2 + (size_t)(cf * 16 + r16) * NF + kcol);
            acc[cf] = MFMA16(a, bv, acc[cf]);
        }
    }
    #pragma unroll
    for (int cf = 0; cf < 8; ++cf) {
        float bv = b2[cf * 16 + r16];
        #pragma unroll
        for (int i = 0; i < 4; ++i) {
            int row = rbase + g4 * 4 + i;
            Y[(size_t)row * NF + cf * 16 + r16] = f2bf(fmaxf(acc[cf][i] + bv, 0.f));
        }
    }
}

// ---------------------------------------------------------------------------
// ENC kernel: blocks [0,64) particle encoder; [64,320) relation encoder with
// in-kernel rel_inputs tile build.
// ---------------------------------------------------------------------------
__global__ __launch_bounds__(256) void enc(
    const u16* __restrict__ P,
    const u16* __restrict__ wp0, const u16* __restrict__ wp1, const u16* __restrict__ wp2,
    const float* __restrict__ pb0, const float* __restrict__ pb1, const float* __restrict__ pb2,
    const u16* __restrict__ wr0, const u16* __restrict__ wr1, const u16* __restrict__ wr2,
    const float* __restrict__ rb0, const float* __restrict__ rb1, const float* __restrict__ rb2,
    const float* __restrict__ attrs, const float* __restrict__ p_inst,
    const int* __restrict__ rr, const int* __restrict__ rs,
    u16* __restrict__ penc, u16* __restrict__ relenc)
{
    __shared__ u16 ri[64 * 64];
    __shared__ u16 tile[4][2][16 * NF];
    int w = threadIdx.x >> 6, lane = threadIdx.x & 63;
    int blk = blockIdx.x;
    if (blk < 64) {
        int rbase = blk * 64 + w * 16;
        enc_body<32, false>(P, nullptr, wp0, wp1, wp2, pb0, pb1, pb2,
                            penc, rbase, w, lane, tile[w][0], tile[w][1]);
        return;
    }
    int blk2 = blk - 64;
    {
        int row = threadIdx.x >> 2;
        int q = threadIdx.x & 3;
        int grow = blk2 * 64 + row;
        int b = grow >> 13;
        int ir = rr[grow], is_ = rs[grow];
        const u16* pr = P + ((size_t)(b << 11) + ir) * 32;
        const u16* ps = P + ((size_t)(b << 11) + is_) * 32;
        float gd = 0.f;
        if (q == 2) {
            #pragma unroll
            for (int k = 0; k < N_INST; ++k) {
                float gr = (ir < N_P) ? p_inst[((size_t)b * N_P + ir) * N_INST + k] : 0.f;
                float gs = (is_ < N_P) ? p_inst[((size_t)b * N_P + is_) * N_INST + k] : 0.f;
                gd += fabsf(gr - gs);
            }
        }
        #pragma unroll
        for (int j = 0; j < 16; ++j) {
            int c = q * 16 + j;
            u16 hv;
            if (c < 19)       hv = pr[c];
            else if (c < 38)  hv = ps[c - 19];
            else if (c < 40)  hv = f2bf(attrs[((size_t)(b << 11) + ir) * 2 + (c - 38)]);
            else if (c < 42)  hv = f2bf(attrs[((size_t)(b << 11) + is_) * 2 + (c - 40)]);
            else if (c == 42) hv = f2bf(gd);
            else if (c < 55)  hv = f2bf(bf2f(pr[c - 41]) - bf2f(ps[c - 41]));
            else if (c == 55) hv = f2bf(bf2f(pr[18]) - bf2f(ps[18]));
            else              hv = 0;
            ri[row * 64 + (c ^ ((row & 7) << 3))] = hv;
        }
    }
    __syncthreads();
    int rbase = blk2 * 64 + w * 16;
    enc_body<64, true>(nullptr, ri, wr0, wr1, wr2, rb0, rb1, rb2,
                       relenc, rbase, w, lane, tile[w][0], tile[w][1]);
}

// ---------------------------------------------------------------------------
// G1: relation propagator, K=384 = [relenc | eff[rr] | eff[rs]], fused scatter
// ---------------------------------------------------------------------------
__global__ __launch_bounds__(256) void g1_rel(
    const u16* __restrict__ relenc, const u16* __restrict__ eff,
    const u16* __restrict__ wt_rp, const float* __restrict__ rp_b,
    const int* __restrict__ rr, const int* __restrict__ rs,
    float* __restrict__ agg)
{
    int lane = threadIdx.x & 63;
    int gw = blockIdx.x * 4 + (threadIdx.x >> 6);
    int rt = gw >> 2, ct = gw & 3;
    int r16 = lane & 15, g4 = lane >> 4;
    int rbase = rt * 32, cbase = ct * 32;

    int idxr[2], idxs[2];
    #pragma unroll
    for (int rf = 0; rf < 2; ++rf) {
        int row = rbase + rf * 16 + r16;
        int b = row >> 13;
        idxr[rf] = (b << 11) + rr[row];
        idxs[rf] = (b << 11) + rs[row];
    }
    f32x4 zero = {0.f, 0.f, 0.f, 0.f};
    f32x4 acc[2][2] = {{zero, zero}, {zero, zero}};

    #pragma unroll
    for (int kf = 0; kf < 12; ++kf) {
        int kcol = kf * 32 + g4 * 8;
        bf16x8 a[2];
        #pragma unroll
        for (int rf = 0; rf < 2; ++rf) {
            int row = rbase + rf * 16 + r16;
            const u16* ap;
            if (kf < 4)      ap = relenc + (size_t)row * NF + kcol;
            else if (kf < 8) ap = eff + (size_t)idxr[rf] * NF + (kcol - NF);
            else             ap = eff + (size_t)idxs[rf] * NF + (kcol - 2 * NF);
            a[rf] = *reinterpret_cast<const bf16x8*>(ap);
        }
        #pragma unroll
        for (int cf = 0; cf < 2; ++cf) {
            bf16x8 bv = *reinterpret_cast<const bf16x8*>(wt_rp + (size_t)(cbase + cf * 16 + r16) * 384 + kcol);
            #pragma unroll
            for (int rf = 0; rf < 2; ++rf)
                acc[rf][cf] = MFMA16(a[rf], bv, acc[rf][cf]);
        }
    }
    #pragma unroll
    for (int rf = 0; rf < 2; ++rf)
        #pragma unroll
        for (int i = 0; i < 4; ++i) {
            int row = rbase + rf * 16 + g4 * 4 + i;
            int dstn = ((row >> 13) << 11) + rr[row];
            float* ap = agg + (size_t)dstn * NF;
            #pragma unroll
            for (int cf = 0; cf < 2; ++cf) {
                int col = cbase + cf * 16 + r16;
                float v = fmaxf(acc[rf][cf][i] + rp_b[col], 0.f);
                atomicAdd(ap + col, v);
            }
        }
}

// ---------------------------------------------------------------------------
// G2: particle propagator. LAST=1 fuses the predictor MLP.
// ---------------------------------------------------------------------------
template<int LAST>
__global__ __launch_bounds__(256) void g2_part(
    const u16* __restrict__ penc, const float* __restrict__ agg,
    const u16* __restrict__ wt_pp, const float* __restrict__ pp_b,
    const u16* __restrict__ eff_prev, u16* __restrict__ eff_out,
    const u16* __restrict__ wn0, const u16* __restrict__ wn1,
    const float* __restrict__ nb0, const float* __restrict__ nb1,
    const float* __restrict__ W2, const float* __restrict__ b2v,
    const float* __restrict__ state, float* __restrict__ out)
{
    __shared__ u16 E[32 * NF];
    __shared__ u16 npt[2][2][16 * NF];
    int lane = threadIdx.x & 63;
    int w = threadIdx.x >> 6;
    int blk = blockIdx.x;
    int r16 = lane & 15, g4 = lane >> 4;
    int rbase = blk * 32, cbase = w * 32;
    f32x4 zero = {0.f, 0.f, 0.f, 0.f};
    f32x4 acc[2][2] = {{zero, zero}, {zero, zero}};

    #pragma unroll
    for (int kf = 0; kf < 8; ++kf) {
        int kcol = kf * 32 + g4 * 8;
        bf16x8 a[2];
        #pragma unroll
        for (int rf = 0; rf < 2; ++rf) {
            int row = rbase + rf * 16 + r16;
            if (kf < 4) {
                a[rf] = *reinterpret_cast<const bf16x8*>(penc + (size_t)row * NF + kcol);
            } else {
                const float* ap = agg + (size_t)row * NF + (kcol - NF);
                float4 lo = *reinterpret_cast<const float4*>(ap);
                float4 hi = *reinterpret_cast<const float4*>(ap + 4);
                bf16x8 t;
                t[0] = (short)f2bf(lo.x); t[1] = (short)f2bf(lo.y);
                t[2] = (short)f2bf(lo.z); t[3] = (short)f2bf(lo.w);
                t[4] = (short)f2bf(hi.x); t[5] = (short)f2bf(hi.y);
                t[6] = (short)f2bf(hi.z); t[7] = (short)f2bf(hi.w);
                a[rf] = t;
            }
        }
        #pragma unroll
        for (int cf = 0; cf < 2; ++cf) {
            bf16x8 bv = *reinterpret_cast<const bf16x8*>(wt_pp + (size_t)(cbase + cf * 16 + r16) * 256 + kcol);
            #pragma unroll
            for (int rf = 0; rf < 2; ++rf)
                acc[rf][cf] = MFMA16(a[rf], bv, acc[rf][cf]);
        }
    }
    #pragma unroll
    for (int rf = 0; rf < 2; ++rf)
        #pragma unroll
        for (int i = 0; i < 4; ++i) {
            int lrow = rf * 16 + g4 * 4 + i;
            int row = rbase + lrow;
            #pragma unroll
            for (int cf = 0; cf < 2; ++cf) {
                int col = cbase + cf * 16 + r16;
                float v = acc[rf][cf][i] + pp_b[col] + bf2f(eff_prev[(size_t)row * NF + col]);
                u16 hv = f2bf(fmaxf(v, 0.f));
                if (LAST) E[lrow * NF + (col ^ ((lrow & 7) << 3))] = hv;
                else      eff_out[(size_t)row * NF + col] = hv;
            }
        }
    if (LAST) {
        __syncthreads();
        if (w < 2) {
            f32x4 acc2[8];
            #pragma unroll
            for (int cf = 0; cf < 8; ++cf) acc2[cf] = zero;
            #pragma unroll
            for (int kf = 0; kf < 4; ++kf) {
                int kcol = kf * 32 + g4 * 8;
                int lr = w * 16 + r16;
                bf16x8 a = *reinterpret_cast<const bf16x8*>(&E[lr * NF + (kcol ^ ((lr & 7) << 3))]);
                #pragma unroll
                for (int cf = 0; cf < 8; ++cf) {
                    bf16x8 bv = *reinterpret_cast<const bf16x8*>(wn0 + (size_t)(cf * 16 + r16) * NF + kcol);
                    acc2[cf] = MFMA16(a, bv, acc2[cf]);
                }
            }
            u16* T0 = npt[w][0];
            #pragma unroll
            for (int cf = 0; cf < 8; ++cf) {
                float bv = nb0[cf * 16 + r16];
                #pragma unroll
                for (int i = 0; i < 4; ++i) {
                    int row = g4 * 4 + i, col = cf * 16 + r16;
                    T0[row * NF + (col ^ ((row & 7) << 3))] = f2bf(fmaxf(acc2[cf][i] + bv, 0.f));
                }
            }
            #pragma unroll
            for (int cf = 0; cf < 8; ++cf) acc2[cf] = zero;
            #pragma unroll
            for (int kf = 0; kf < 4; ++kf) {
                int kcol = kf * 32 + g4 * 8;
                bf16x8 a = *reinterpret_cast<const bf16x8*>(&T0[r16 * NF + (kcol ^ ((r16 & 7) << 3))]);
                #pragma unroll
                for (int cf = 0; cf < 8; ++cf) {
                    bf16x8 bv = *reinterpret_cast<const bf16x8*>(wn1 + (size_t)(cf * 16 + r16) * NF + kcol);
                    acc2[cf] = MFMA16(a, bv, acc2[cf]);
                }
            }
            u16* T1 = npt[w][1];
            #pragma unroll
            for (int cf = 0; cf < 8; ++cf) {
                float bv = nb1[cf * 16 + r16];
                #pragma unroll
                for (int i = 0; i < 4; ++i) {
                    int row = g4 * 4 + i, col = cf * 16 + r16;
                    T1[row * NF + (col ^ ((row & 7) << 3))] = f2bf(fmaxf(acc2[cf][i] + bv, 0.f));
                }
            }
            if (g4 < 3) {
                int grow = rbase + w * 16 + r16;
                int b = grow >> 11, n = grow & 2047;
                if (n < N_P) {
                    float s = b2v[g4];
                    for (int k = 0; k < NF; ++k)
                        s += bf2f(T1[r16 * NF + (k ^ ((r16 & 7) << 3))]) * W2[k * 3 + g4];
                    s = fminf(fmaxf(s, -100.f), 100.f);
                    out[((size_t)b * N_P + n) * 3 + g4] =
                        s + state[(((size_t)b * 4 + 3) * N_ALL + n) * 3 + g4];
                }
            }
        }
    }
}

// ---------------------------------------------------------------------------
extern "C" void kernel_launch(void* const* d_in, const int* in_sizes, int n_in,
                              void* d_out, int out_size, void* d_ws, size_t ws_size,
                              hipStream_t stream) {
    (void)in_sizes; (void)n_in; (void)out_size; (void)ws_size;
    const float* state      = (const float*)d_in[0];
    const float* attrs      = (const float*)d_in[1];
    const float* Rr         = (const float*)d_in[2];
    const float* Rs         = (const float*)d_in[3];
    const float* p_instance = (const float*)d_in[4];
    const float* action     = (const float*)d_in[5];
    const float* den        = (const float*)d_in[6];
    const float* phys       = (const float*)d_in[7];
    const float* pe_W0 = (const float*)d_in[8];  const float* pe_b0 = (const float*)d_in[9];
    const float* pe_W1 = (const float*)d_in[10]; const float* pe_b1 = (const float*)d_in[11];
    const float* pe_W2 = (const float*)d_in[12]; const float* pe_b2 = (const float*)d_in[13];
    const float* re_W0 = (const float*)d_in[14]; const float* re_b0 = (const float*)d_in[15];
    const float* re_W1 = (const float*)d_in[16]; const float* re_b1 = (const float*)d_in[17];
    const float* re_W2 = (const float*)d_in[18]; const float* re_b2 = (const float*)d_in[19];
    const float* pp_W  = (const float*)d_in[20]; const float* pp_b  = (const float*)d_in[21];
    const float* rp_W  = (const float*)d_in[22]; const float* rp_b  = (const float*)d_in[23];
    const float* np_W0 = (const float*)d_in[24]; const float* np_b0 = (const float*)d_in[25];
    const float* np_W1 = (const float*)d_in[26]; const float* np_b1 = (const float*)d_in[27];
    const float* np_W2 = (const float*)d_in[28]; const float* np_b2 = (const float*)d_in[29];

    char* base = (char*)d_ws;
    size_t off = 0;
    auto alloc = [&](size_t bytes) -> void* {
        off = (off + 255) & ~(size_t)255;
        void* p = base + off; off += bytes; return p;
    };
    int* rr      = (int*)alloc(B * N_REL * 4);
    int* rs      = (int*)alloc(B * N_REL * 4);
    u16* P       = (u16*)alloc((size_t)B * N_ALL * 32 * 2);
    u16* penc    = (u16*)alloc((size_t)B * N_ALL * NF * 2);
    u16* relenc  = (u16*)alloc((size_t)B * N_REL * NF * 2);
    u16* effA    = (u16*)alloc((size_t)B * N_ALL * NF * 2);
    u16* effB    = (u16*)alloc((size_t)B * N_ALL * NF * 2);
    float* agg3  = (float*)alloc((size_t)3 * B * N_ALL * NF * 4);

    WtCvt d;
    const float* srcs[10] = {pe_W0, pe_W1, pe_W2, re_W0, re_W1, re_W2, pp_W, rp_W, np_W0, np_W1};
    const int Ks[10]  = {19, 128, 128, 56, 128, 128, 256, 384, 128, 128};
    const int Kps[10] = {32, 128, 128, 64, 128, 128, 256, 384, 128, 128};
    d.cum[0] = 0;
    for (int i = 0; i < 10; ++i) {
        d.src[i] = srcs[i]; d.K[i] = Ks[i]; d.Kpad[i] = Kps[i];
        d.cum[i + 1] = d.cum[i] + NF * Kps[i];
    }
    int wt_total = d.cum[10];
    u16* wt = (u16*)alloc((size_t)wt_total * 2);

    const int RN = B * N_ALL;    // 4096
    const int RE = B * N_REL;    // 16384
    const int aggz_f4 = 3 * RN * NF / 4;

    prep<<<PREP_TOTAL, 256, 0, stream>>>(Rr, rr, d, wt, wt_total,
                                         state, attrs, action, den, phys, P,
                                         agg3, aggz_f4);
    scan_rs<<<PREP_SCAN_BLKS, 256, 0, stream>>>(Rs, rs);

    enc<<<64 + RE / 64, 256, 0, stream>>>(P,
        wt + d.cum[0], wt + d.cum[1], wt + d.cum[2], pe_b0, pe_b1, pe_b2,
        wt + d.cum[3], wt + d.cum[4], wt + d.cum[5], re_b0, re_b1, re_b2,
        attrs, p_instance, rr, rs, penc, relenc);

    const u16* effin = penc;
    u16* outbuf[3] = {effA, effB, effA};
    for (int s = 0; s < 3; ++s) {
        float* agg = agg3 + (size_t)s * RN * NF;
        g1_rel<<<RE / 32, 256, 0, stream>>>(relenc, effin, wt + d.cum[7], rp_b, rr, rs, agg);
        if (s < 2)
            g2_part<0><<<RN / 32, 256, 0, stream>>>(penc, agg, wt + d.cum[6], pp_b, effin, outbuf[s],
                wt + d.cum[8], wt + d.cum[9], np_b0, np_b1, np_W2, np_b2, state, (float*)d_out);
        else
            g2_part<1><<<RN / 32, 256, 0, stream>>>(penc, agg, wt + d.cum[6], pp_b, effin, outbuf[s],
                wt + d.cum[8], wt + d.cum[9], np_b0, np_b1, np_W2, np_b2, state, (float*)d_out);
        effin = outbuf[s];
    }
}

// Round 6
// 156.599 us; speedup vs baseline: 1.0205x; 1.0205x over previous
//
#include <hip/hip_runtime.h>

#define B 2
#define N_P 2000
#define N_ALL 2048
#define N_REL 8192
#define N_INST 8
#define NF 128

typedef unsigned short u16;
typedef __attribute__((ext_vector_type(8))) short bf16x8;
typedef __attribute__((ext_vector_type(4))) float f32x4;

__device__ __forceinline__ u16 f2bf(float f) {
    union { float f; unsigned u; } v; v.f = f;
    unsigned r = v.u + 0x7FFFu + ((v.u >> 16) & 1u);
    return (u16)(r >> 16);
}
__device__ __forceinline__ float bf2f(u16 h) {
    union { unsigned u; float f; } v; v.u = ((unsigned)h) << 16; return v.f;
}

#define MFMA16(a, b, c) __builtin_amdgcn_mfma_f32_16x16x32_bf16((a), (b), (c), 0, 0, 0)

struct WtCvt {
    const float* src[10];
    int K[10];
    int Kpad[10];
    int cum[11];
};

// ---------------------------------------------------------------------------
// Forced-MLP scan burst: 2 rows (16 x 1KB loads) issued via inline asm so the
// compiler MUST keep 16 results in flight; one vmcnt(0) drain; sched_barrier
// pins the compares after the wait (rule: "memory" clobber does not order
// register-only consumers).
// ---------------------------------------------------------------------------
__device__ __forceinline__ void scan_burst(const float* __restrict__ rowbase, int lane,
                                           int& fa, int& fb)
{
    f32x4 v[16];
    const float* lb = rowbase + lane * 4;
    #pragma unroll
    for (int i = 0; i < 16; ++i) {
        const float* p = lb + (i >> 3) * N_ALL + (i & 7) * 256;
        asm volatile("global_load_dwordx4 %0, %1, off" : "=v"(v[i]) : "v"(p));
    }
    asm volatile("s_waitcnt vmcnt(0)" ::: "memory");
    __builtin_amdgcn_sched_barrier(0);
    fa = -1; fb = -1;
    #pragma unroll
    for (int i = 0; i < 8; ++i) {
        int bi = i * 256 + lane * 4;
        if (v[i].x != 0.f) fa = bi;
        if (v[i].y != 0.f) fa = bi + 1;
        if (v[i].z != 0.f) fa = bi + 2;
        if (v[i].w != 0.f) fa = bi + 3;
    }
    #pragma unroll
    for (int i = 8; i < 16; ++i) {
        int bi = (i - 8) * 256 + lane * 4;
        if (v[i].x != 0.f) fb = bi;
        if (v[i].y != 0.f) fb = bi + 1;
        if (v[i].z != 0.f) fb = bi + 2;
        if (v[i].w != 0.f) fb = bi + 3;
    }
}

// ---------------------------------------------------------------------------
// PREP kernel, block-ranged fusion:
//   [0, 2048):      scan of Rr+Rs (8192 waves x 4 rows, 2 bursts each)
//   [2048, 2800):   weight convert fp32 [K][128] -> bf16 [128][Kpad]
//   [2800, 2816):   build p_inputs bf16 [B*N_ALL][32]
//   [2816, 4352):   zero 3 agg buffers
// ---------------------------------------------------------------------------
#define PREP_SCAN_BLKS 2048
#define PREP_CVT_BLKS  752
#define PREP_PIN_BLKS  16
#define PREP_ZERO_BLKS 1536
#define PREP_TOTAL (PREP_SCAN_BLKS + PREP_CVT_BLKS + PREP_PIN_BLKS + PREP_ZERO_BLKS)

__global__ __launch_bounds__(256, 1) void prep(
    const float* __restrict__ Rr, const float* __restrict__ Rs,
    int* __restrict__ rr, int* __restrict__ rs,
    WtCvt d, u16* __restrict__ wt, int wt_total,
    const float* __restrict__ state, const float* __restrict__ attrs,
    const float* __restrict__ action, const float* __restrict__ den,
    const float* __restrict__ phys, u16* __restrict__ P,
    float* __restrict__ aggz, int aggz_f4)
{
    int blk = blockIdx.x;
    if (blk < PREP_SCAN_BLKS) {
        int gw = blk * 4 + (threadIdx.x >> 6);   // 0..8191
        int lane = threadIdx.x & 63;
        int r0 = gw * 4;                          // 4 rows, single matrix (split at 16384)
        const float* M;
        int* out;
        int e;
        if (r0 < 16384) { M = Rr + (size_t)r0 * N_ALL; out = rr; e = r0; }
        else            { M = Rs + (size_t)(r0 - 16384) * N_ALL; out = rs; e = r0 - 16384; }
        int f0, f1, f2, f3;
        scan_burst(M,             lane, f0, f1);
        scan_burst(M + 2 * N_ALL, lane, f2, f3);
        #pragma unroll
        for (int off = 32; off; off >>= 1) {
            f0 = max(f0, __shfl_xor(f0, off));
            f1 = max(f1, __shfl_xor(f1, off));
            f2 = max(f2, __shfl_xor(f2, off));
            f3 = max(f3, __shfl_xor(f3, off));
        }
        if (lane == 0) {
            int4 o; o.x = f0; o.y = f1; o.z = f2; o.w = f3;
            *reinterpret_cast<int4*>(out + e) = o;
        }
        return;
    }
    blk -= PREP_SCAN_BLKS;
    if (blk < PREP_CVT_BLKS) {
        int t = blk * 256 + threadIdx.x;
        if (t >= wt_total) return;
        int m = 0;
        while (t >= d.cum[m + 1]) m++;
        int loc = t - d.cum[m];
        int Kp = d.Kpad[m];
        int c = loc / Kp, k = loc - c * Kp;
        float v = (k < d.K[m]) ? d.src[m][(size_t)k * NF + c] : 0.f;
        wt[t] = f2bf(v);
        return;
    }
    blk -= PREP_CVT_BLKS;
    if (blk < PREP_PIN_BLKS) {
        int t = blk * 256 + threadIdx.x;
        if (t >= B * N_ALL) return;
        int b = t >> 11, n = t & 2047;
        float o[19];
        o[0] = attrs[t * 2]; o[1] = attrs[t * 2 + 1];
        #pragma unroll
        for (int h = 0; h < 3; ++h)
            #pragma unroll
            for (int c = 0; c < 3; ++c)
                o[2 + h * 3 + c] = state[(((size_t)b * 4 + h + 1) * N_ALL + n) * 3 + c]
                                 - state[(((size_t)b * 4 + h)     * N_ALL + n) * 3 + c];
        #pragma unroll
        for (int c = 0; c < 3; ++c)
            o[11 + c] = state[(((size_t)b * 4 + 3) * N_ALL + n) * 3 + c];
        o[14] = (n < N_P) ? phys[b] : 0.f;
        #pragma unroll
        for (int c = 0; c < 3; ++c) o[15 + c] = action[t * 3 + c];
        o[18] = (n < N_P) ? den[b] : 0.f;
        u16* dst = P + (size_t)t * 32;
        #pragma unroll
        for (int k = 0; k < 19; ++k) dst[k] = f2bf(o[k]);
        #pragma unroll
        for (int k = 19; k < 32; ++k) dst[k] = 0;
        return;
    }
    blk -= PREP_PIN_BLKS;
    {
        int t = blk * 256 + threadIdx.x;
        if (t < aggz_f4) {
            f32x4 z = {0.f, 0.f, 0.f, 0.f};
            reinterpret_cast<f32x4*>(aggz)[t] = z;
        }
    }
}

// ---------------------------------------------------------------------------
// Shared 3-layer MLP body (wave = 16 rows x 128 cols)
// ---------------------------------------------------------------------------
template<int K0, bool ALDS>
__device__ __forceinline__ void enc_body(
    const u16* __restrict__ Xg, const u16* ri,
    const u16* __restrict__ wt0, const u16* __restrict__ wt1, const u16* __restrict__ wt2,
    const float* __restrict__ b0, const float* __restrict__ b1, const float* __restrict__ b2,
    u16* __restrict__ Y, int rbase, int w, int lane, u16* T0, u16* T1)
{
    int r16 = lane & 15, g4 = lane >> 4;
    f32x4 zero = {0.f, 0.f, 0.f, 0.f};
    f32x4 acc[8];
    #pragma unroll
    for (int cf = 0; cf < 8; ++cf) acc[cf] = zero;
    #pragma unroll
    for (int kf = 0; kf < K0 / 32; ++kf) {
        int kcol = kf * 32 + g4 * 8;
        bf16x8 a;
        if (ALDS) {
            int lr = w * 16 + r16;
            a = *reinterpret_cast<const bf16x8*>(&ri[lr * K0 + (kcol ^ ((lr & 7) << 3))]);
        } else {
            a = *reinterpret_cast<const bf16x8*>(Xg + (size_t)(rbase + r16) * K0 + kcol);
        }
        #pragma unroll
        for (int cf = 0; cf < 8; ++cf) {
            bf16x8 bv = *reinterpret_cast<const bf16x8*>(wt0 + (size_t)(cf * 16 + r16) * K0 + kcol);
            acc[cf] = MFMA16(a, bv, acc[cf]);
        }
    }
    #pragma unroll
    for (int cf = 0; cf < 8; ++cf) {
        float bv = b0[cf * 16 + r16];
        #pragma unroll
        for (int i = 0; i < 4; ++i) {
            int row = g4 * 4 + i, col = cf * 16 + r16;
            T0[row * NF + (col ^ ((row & 7) << 3))] = f2bf(fmaxf(acc[cf][i] + bv, 0.f));
        }
    }
    #pragma unroll
    for (int cf = 0; cf < 8; ++cf) acc[cf] = zero;
    #pragma unroll
    for (int kf = 0; kf < 4; ++kf) {
        int kcol = kf * 32 + g4 * 8;
        bf16x8 a = *reinterpret_cast<const bf16x8*>(&T0[r16 * NF + (kcol ^ ((r16 & 7) << 3))]);
        #pragma unroll
        for (int cf = 0; cf < 8; ++cf) {
            bf16x8 bv = *reinterpret_cast<const bf16x8*>(wt1 + (size_t)(cf * 16 + r16) * NF + kcol);
            acc[cf] = MFMA16(a, bv, acc[cf]);
        }
    }
    #pragma unroll
    for (int cf = 0; cf < 8; ++cf) {
        float bv = b1[cf * 16 + r16];
        #pragma unroll
        for (int i = 0; i < 4; ++i) {
            int row = g4 * 4 + i, col = cf * 16 + r16;
            T1[row * NF + (col ^ ((row & 7) << 3))] = f2bf(fmaxf(acc[cf][i] + bv, 0.f));
        }
    }
    #pragma unroll
    for (int cf = 0; cf < 8; ++cf) acc[cf] = zero;
    #pragma unroll
    for (int kf = 0; kf < 4; ++kf) {
        int kcol = kf * 32 + g4 * 8;
        bf16x8 a = *reinterpret_cast<const bf16x8*>(&T1[r16 * NF + (kcol ^ ((r16 & 7) << 3))]);
        #pragma unroll
        for (int cf = 0; cf < 8; ++cf) {
            bf16x8 bv = *reinterpret_cast<const bf16x8*>(wt2 + (size_t)(cf * 16 + r16) * NF + kcol);
            acc[cf] = MFMA16(a, bv, acc[cf]);
        }
    }
    #pragma unroll
    for (int cf = 0; cf < 8; ++cf) {
        float bv = b2[cf * 16 + r16];
        #pragma unroll
        for (int i = 0; i < 4; ++i) {
            int row = rbase + g4 * 4 + i;
            Y[(size_t)row * NF + cf * 16 + r16] = f2bf(fmaxf(acc[cf][i] + bv, 0.f));
        }
    }
}

// ---------------------------------------------------------------------------
// ENC kernel: blocks [0,64) particle encoder; [64,320) relation encoder with
// in-kernel rel_inputs tile build.
// ---------------------------------------------------------------------------
__global__ __launch_bounds__(256) void enc(
    const u16* __restrict__ P,
    const u16* __restrict__ wp0, const u16* __restrict__ wp1, const u16* __restrict__ wp2,
    const float* __restrict__ pb0, const float* __restrict__ pb1, const float* __restrict__ pb2,
    const u16* __restrict__ wr0, const u16* __restrict__ wr1, const u16* __restrict__ wr2,
    const float* __restrict__ rb0, const float* __restrict__ rb1, const float* __restrict__ rb2,
    const float* __restrict__ attrs, const float* __restrict__ p_inst,
    const int* __restrict__ rr, const int* __restrict__ rs,
    u16* __restrict__ penc, u16* __restrict__ relenc)
{
    __shared__ u16 ri[64 * 64];
    __shared__ u16 tile[4][2][16 * NF];
    int w = threadIdx.x >> 6, lane = threadIdx.x & 63;
    int blk = blockIdx.x;
    if (blk < 64) {
        int rbase = blk * 64 + w * 16;
        enc_body<32, false>(P, nullptr, wp0, wp1, wp2, pb0, pb1, pb2,
                            penc, rbase, w, lane, tile[w][0], tile[w][1]);
        return;
    }
    int blk2 = blk - 64;
    {
        int row = threadIdx.x >> 2;
        int q = threadIdx.x & 3;
        int grow = blk2 * 64 + row;
        int b = grow >> 13;
        int ir = rr[grow], is_ = rs[grow];
        const u16* pr = P + ((size_t)(b << 11) + ir) * 32;
        const u16* ps = P + ((size_t)(b << 11) + is_) * 32;
        float gd = 0.f;
        if (q == 2) {
            #pragma unroll
            for (int k = 0; k < N_INST; ++k) {
                float gr = (ir < N_P) ? p_inst[((size_t)b * N_P + ir) * N_INST + k] : 0.f;
                float gs = (is_ < N_P) ? p_inst[((size_t)b * N_P + is_) * N_INST + k] : 0.f;
                gd += fabsf(gr - gs);
            }
        }
        #pragma unroll
        for (int j = 0; j < 16; ++j) {
            int c = q * 16 + j;
            u16 hv;
            if (c < 19)       hv = pr[c];
            else if (c < 38)  hv = ps[c - 19];
            else if (c < 40)  hv = f2bf(attrs[((size_t)(b << 11) + ir) * 2 + (c - 38)]);
            else if (c < 42)  hv = f2bf(attrs[((size_t)(b << 11) + is_) * 2 + (c - 40)]);
            else if (c == 42) hv = f2bf(gd);
            else if (c < 55)  hv = f2bf(bf2f(pr[c - 41]) - bf2f(ps[c - 41]));
            else if (c == 55) hv = f2bf(bf2f(pr[18]) - bf2f(ps[18]));
            else              hv = 0;
            ri[row * 64 + (c ^ ((row & 7) << 3))] = hv;
        }
    }
    __syncthreads();
    int rbase = blk2 * 64 + w * 16;
    enc_body<64, true>(nullptr, ri, wr0, wr1, wr2, rb0, rb1, rb2,
                       relenc, rbase, w, lane, tile[w][0], tile[w][1]);
}

// ---------------------------------------------------------------------------
// G1: relation propagator, K=384 = [relenc | eff[rr] | eff[rs]], fused scatter
// ---------------------------------------------------------------------------
__global__ __launch_bounds__(256) void g1_rel(
    const u16* __restrict__ relenc, const u16* __restrict__ eff,
    const u16* __restrict__ wt_rp, const float* __restrict__ rp_b,
    const int* __restrict__ rr, const int* __restrict__ rs,
    float* __restrict__ agg)
{
    int lane = threadIdx.x & 63;
    int gw = blockIdx.x * 4 + (threadIdx.x >> 6);
    int rt = gw >> 2, ct = gw & 3;
    int r16 = lane & 15, g4 = lane >> 4;
    int rbase = rt * 32, cbase = ct * 32;

    int idxr[2], idxs[2];
    #pragma unroll
    for (int rf = 0; rf < 2; ++rf) {
        int row = rbase + rf * 16 + r16;
        int b = row >> 13;
        idxr[rf] = (b << 11) + rr[row];
        idxs[rf] = (b << 11) + rs[row];
    }
    f32x4 zero = {0.f, 0.f, 0.f, 0.f};
    f32x4 acc[2][2] = {{zero, zero}, {zero, zero}};

    #pragma unroll
    for (int kf = 0; kf < 12; ++kf) {
        int kcol = kf * 32 + g4 * 8;
        bf16x8 a[2];
        #pragma unroll
        for (int rf = 0; rf < 2; ++rf) {
            int row = rbase + rf * 16 + r16;
            const u16* ap;
            if (kf < 4)      ap = relenc + (size_t)row * NF + kcol;
            else if (kf < 8) ap = eff + (size_t)idxr[rf] * NF + (kcol - NF);
            else             ap = eff + (size_t)idxs[rf] * NF + (kcol - 2 * NF);
            a[rf] = *reinterpret_cast<const bf16x8*>(ap);
        }
        #pragma unroll
        for (int cf = 0; cf < 2; ++cf) {
            bf16x8 bv = *reinterpret_cast<const bf16x8*>(wt_rp + (size_t)(cbase + cf * 16 + r16) * 384 + kcol);
            #pragma unroll
            for (int rf = 0; rf < 2; ++rf)
                acc[rf][cf] = MFMA16(a[rf], bv, acc[rf][cf]);
        }
    }
    #pragma unroll
    for (int rf = 0; rf < 2; ++rf)
        #pragma unroll
        for (int i = 0; i < 4; ++i) {
            int row = rbase + rf * 16 + g4 * 4 + i;
            int dstn = ((row >> 13) << 11) + rr[row];
            float* ap = agg + (size_t)dstn * NF;
            #pragma unroll
            for (int cf = 0; cf < 2; ++cf) {
                int col = cbase + cf * 16 + r16;
                float v = fmaxf(acc[rf][cf][i] + rp_b[col], 0.f);
                atomicAdd(ap + col, v);
            }
        }
}

// ---------------------------------------------------------------------------
// G2: particle propagator. LAST=1 fuses the predictor MLP.
// ---------------------------------------------------------------------------
template<int LAST>
__global__ __launch_bounds__(256) void g2_part(
    const u16* __restrict__ penc, const float* __restrict__ agg,
    const u16* __restrict__ wt_pp, const float* __restrict__ pp_b,
    const u16* __restrict__ eff_prev, u16* __restrict__ eff_out,
    const u16* __restrict__ wn0, const u16* __restrict__ wn1,
    const float* __restrict__ nb0, const float* __restrict__ nb1,
    const float* __restrict__ W2, const float* __restrict__ b2v,
    const float* __restrict__ state, float* __restrict__ out)
{
    __shared__ u16 E[32 * NF];
    __shared__ u16 npt[2][2][16 * NF];
    int lane = threadIdx.x & 63;
    int w = threadIdx.x >> 6;
    int blk = blockIdx.x;
    int r16 = lane & 15, g4 = lane >> 4;
    int rbase = blk * 32, cbase = w * 32;
    f32x4 zero = {0.f, 0.f, 0.f, 0.f};
    f32x4 acc[2][2] = {{zero, zero}, {zero, zero}};

    #pragma unroll
    for (int kf = 0; kf < 8; ++kf) {
        int kcol = kf * 32 + g4 * 8;
        bf16x8 a[2];
        #pragma unroll
        for (int rf = 0; rf < 2; ++rf) {
            int row = rbase + rf * 16 + r16;
            if (kf < 4) {
                a[rf] = *reinterpret_cast<const bf16x8*>(penc + (size_t)row * NF + kcol);
            } else {
                const float* ap = agg + (size_t)row * NF + (kcol - NF);
                float4 lo = *reinterpret_cast<const float4*>(ap);
                float4 hi = *reinterpret_cast<const float4*>(ap + 4);
                bf16x8 t;
                t[0] = (short)f2bf(lo.x); t[1] = (short)f2bf(lo.y);
                t[2] = (short)f2bf(lo.z); t[3] = (short)f2bf(lo.w);
                t[4] = (short)f2bf(hi.x); t[5] = (short)f2bf(hi.y);
                t[6] = (short)f2bf(hi.z); t[7] = (short)f2bf(hi.w);
                a[rf] = t;
            }
        }
        #pragma unroll
        for (int cf = 0; cf < 2; ++cf) {
            bf16x8 bv = *reinterpret_cast<const bf16x8*>(wt_pp + (size_t)(cbase + cf * 16 + r16) * 256 + kcol);
            #pragma unroll
            for (int rf = 0; rf < 2; ++rf)
                acc[rf][cf] = MFMA16(a[rf], bv, acc[rf][cf]);
        }
    }
    #pragma unroll
    for (int rf = 0; rf < 2; ++rf)
        #pragma unroll
        for (int i = 0; i < 4; ++i) {
            int lrow = rf * 16 + g4 * 4 + i;
            int row = rbase + lrow;
            #pragma unroll
            for (int cf = 0; cf < 2; ++cf) {
                int col = cbase + cf * 16 + r16;
                float v = acc[rf][cf][i] + pp_b[col] + bf2f(eff_prev[(size_t)row * NF + col]);
                u16 hv = f2bf(fmaxf(v, 0.f));
                if (LAST) E[lrow * NF + (col ^ ((lrow & 7) << 3))] = hv;
                else      eff_out[(size_t)row * NF + col] = hv;
            }
        }
    if (LAST) {
        __syncthreads();
        if (w < 2) {
            f32x4 acc2[8];
            #pragma unroll
            for (int cf = 0; cf < 8; ++cf) acc2[cf] = zero;
            #pragma unroll
            for (int kf = 0; kf < 4; ++kf) {
                int kcol = kf * 32 + g4 * 8;
                int lr = w * 16 + r16;
                bf16x8 a = *reinterpret_cast<const bf16x8*>(&E[lr * NF + (kcol ^ ((lr & 7) << 3))]);
                #pragma unroll
                for (int cf = 0; cf < 8; ++cf) {
                    bf16x8 bv = *reinterpret_cast<const bf16x8*>(wn0 + (size_t)(cf * 16 + r16) * NF + kcol);
                    acc2[cf] = MFMA16(a, bv, acc2[cf]);
                }
            }
            u16* T0 = npt[w][0];
            #pragma unroll
            for (int cf = 0; cf < 8; ++cf) {
                float bv = nb0[cf * 16 + r16];
                #pragma unroll
                for (int i = 0; i < 4; ++i) {
                    int row = g4 * 4 + i, col = cf * 16 + r16;
                    T0[row * NF + (col ^ ((row & 7) << 3))] = f2bf(fmaxf(acc2[cf][i] + bv, 0.f));
                }
            }
            #pragma unroll
            for (int cf = 0; cf < 8; ++cf) acc2[cf] = zero;
            #pragma unroll
            for (int kf = 0; kf < 4; ++kf) {
                int kcol = kf * 32 + g4 * 8;
                bf16x8 a = *reinterpret_cast<const bf16x8*>(&T0[r16 * NF + (kcol ^ ((r16 & 7) << 3))]);
                #pragma unroll
                for (int cf = 0; cf < 8; ++cf) {
                    bf16x8 bv = *reinterpret_cast<const bf16x8*>(wn1 + (size_t)(cf * 16 + r16) * NF + kcol);
                    acc2[cf] = MFMA16(a, bv, acc2[cf]);
                }
            }
            u16* T1 = npt[w][1];
            #pragma unroll
            for (int cf = 0; cf < 8; ++cf) {
                float bv = nb1[cf * 16 + r16];
                #pragma unroll
                for (int i = 0; i < 4; ++i) {
                    int row = g4 * 4 + i, col = cf * 16 + r16;
                    T1[row * NF + (col ^ ((row & 7) << 3))] = f2bf(fmaxf(acc2[cf][i] + bv, 0.f));
                }
            }
            if (g4 < 3) {
                int grow = rbase + w * 16 + r16;
                int b = grow >> 11, n = grow & 2047;
                if (n < N_P) {
                    float s = b2v[g4];
                    for (int k = 0; k < NF; ++k)
                        s += bf2f(T1[r16 * NF + (k ^ ((r16 & 7) << 3))]) * W2[k * 3 + g4];
                    s = fminf(fmaxf(s, -100.f), 100.f);
                    out[((size_t)b * N_P + n) * 3 + g4] =
                        s + state[(((size_t)b * 4 + 3) * N_ALL + n) * 3 + g4];
                }
            }
        }
    }
}

// ---------------------------------------------------------------------------
extern "C" void kernel_launch(void* const* d_in, const int* in_sizes, int n_in,
                              void* d_out, int out_size, void* d_ws, size_t ws_size,
                              hipStream_t stream) {
    (void)in_sizes; (void)n_in; (void)out_size; (void)ws_size;
    const float* state      = (const float*)d_in[0];
    const float* attrs      = (const float*)d_in[1];
    const float* Rr         = (const float*)d_in[2];
    const float* Rs         = (const float*)d_in[3];
    const float* p_instance = (const float*)d_in[4];
    const float* action     = (const float*)d_in[5];
    const float* den        = (const float*)d_in[6];
    const float* phys       = (const float*)d_in[7];
    const float* pe_W0 = (const float*)d_in[8];  const float* pe_b0 = (const float*)d_in[9];
    const float* pe_W1 = (const float*)d_in[10]; const float* pe_b1 = (const float*)d_in[11];
    const float* pe_W2 = (const float*)d_in[12]; const float* pe_b2 = (const float*)d_in[13];
    const float* re_W0 = (const float*)d_in[14]; const float* re_b0 = (const float*)d_in[15];
    const float* re_W1 = (const float*)d_in[16]; const float* re_b1 = (const float*)d_in[17];
    const float* re_W2 = (const float*)d_in[18]; const float* re_b2 = (const float*)d_in[19];
    const float* pp_W  = (const float*)d_in[20]; const float* pp_b  = (const float*)d_in[21];
    const float* rp_W  = (const float*)d_in[22]; const float* rp_b  = (const float*)d_in[23];
    const float* np_W0 = (const float*)d_in[24]; const float* np_b0 = (const float*)d_in[25];
    const float* np_W1 = (const float*)d_in[26]; const float* np_b1 = (const float*)d_in[27];
    const float* np_W2 = (const float*)d_in[28]; const float* np_b2 = (const float*)d_in[29];

    char* base = (char*)d_ws;
    size_t off = 0;
    auto alloc = [&](size_t bytes) -> void* {
        off = (off + 255) & ~(size_t)255;
        void* p = base + off; off += bytes; return p;
    };
    int* rr      = (int*)alloc(B * N_REL * 4);
    int* rs      = (int*)alloc(B * N_REL * 4);
    u16* P       = (u16*)alloc((size_t)B * N_ALL * 32 * 2);
    u16* penc    = (u16*)alloc((size_t)B * N_ALL * NF * 2);
    u16* relenc  = (u16*)alloc((size_t)B * N_REL * NF * 2);
    u16* effA    = (u16*)alloc((size_t)B * N_ALL * NF * 2);
    u16* effB    = (u16*)alloc((size_t)B * N_ALL * NF * 2);
    float* agg3  = (float*)alloc((size_t)3 * B * N_ALL * NF * 4);

    WtCvt d;
    const float* srcs[10] = {pe_W0, pe_W1, pe_W2, re_W0, re_W1, re_W2, pp_W, rp_W, np_W0, np_W1};
    const int Ks[10]  = {19, 128, 128, 56, 128, 128, 256, 384, 128, 128};
    const int Kps[10] = {32, 128, 128, 64, 128, 128, 256, 384, 128, 128};
    d.cum[0] = 0;
    for (int i = 0; i < 10; ++i) {
        d.src[i] = srcs[i]; d.K[i] = Ks[i]; d.Kpad[i] = Kps[i];
        d.cum[i + 1] = d.cum[i] + NF * Kps[i];
    }
    int wt_total = d.cum[10];
    u16* wt = (u16*)alloc((size_t)wt_total * 2);

    const int RN = B * N_ALL;    // 4096
    const int RE = B * N_REL;    // 16384
    const int aggz_f4 = 3 * RN * NF / 4;

    prep<<<PREP_TOTAL, 256, 0, stream>>>(Rr, Rs, rr, rs, d, wt, wt_total,
                                         state, attrs, action, den, phys, P,
                                         agg3, aggz_f4);

    enc<<<64 + RE / 64, 256, 0, stream>>>(P,
        wt + d.cum[0], wt + d.cum[1], wt + d.cum[2], pe_b0, pe_b1, pe_b2,
        wt + d.cum[3], wt + d.cum[4], wt + d.cum[5], re_b0, re_b1, re_b2,
        attrs, p_instance, rr, rs, penc, relenc);

    const u16* effin = penc;
    u16* outbuf[3] = {effA, effB, effA};
    for (int s = 0; s < 3; ++s) {
        float* agg = agg3 + (size_t)s * RN * NF;
        g1_rel<<<RE / 32, 256, 0, stream>>>(relenc, effin, wt + d.cum[7], rp_b, rr, rs, agg);
        if (s < 2)
            g2_part<0><<<RN / 32, 256, 0, stream>>>(penc, agg, wt + d.cum[6], pp_b, effin, outbuf[s],
                wt + d.cum[8], wt + d.cum[9], np_b0, np_b1, np_W2, np_b2, state, (float*)d_out);
        else
            g2_part<1><<<RN / 32, 256, 0, stream>>>(penc, agg, wt + d.cum[6], pp_b, effin, outbuf[s],
                wt + d.cum[8], wt + d.cum[9], np_b0, np_b1, np_W2, np_b2, state, (float*)d_out);
        effin = outbuf[s];
    }
}